// Round 1
// baseline (415.337 us; speedup 1.0000x reference)
//
#include <hip/hip_runtime.h>
#include <stdint.h>

typedef __attribute__((ext_vector_type(8))) short bf16x8;   // 8 bf16 = 4 VGPRs
typedef __attribute__((ext_vector_type(4))) float f32x4;

#define DEVI __device__ __forceinline__

DEVI unsigned short f2bf(float f) {
    union { float f; uint32_t u; } v; v.f = f;
    uint32_t r = v.u + 0x7FFFu + ((v.u >> 16) & 1u);   // RNE, no NaN handling needed
    return (unsigned short)(r >> 16);
}
DEVI float bf2f(unsigned short h) {
    union { uint32_t u; float f; } v; v.u = ((uint32_t)h) << 16;
    return v.f;
}
DEVI bf16x8 pack8(float4 a, float4 b) {
    bf16x8 o;
    o[0]=(short)f2bf(a.x); o[1]=(short)f2bf(a.y); o[2]=(short)f2bf(a.z); o[3]=(short)f2bf(a.w);
    o[4]=(short)f2bf(b.x); o[5]=(short)f2bf(b.y); o[6]=(short)f2bf(b.z); o[7]=(short)f2bf(b.w);
    return o;
}

// async global->LDS, 16B per lane; LDS dest must be wave-uniform base (+lane*16 by HW)
#define GLOAD_LDS16(gsrc, ldst) \
    __builtin_amdgcn_global_load_lds((__attribute__((address_space(1))) void*)(gsrc), \
                                     (__attribute__((address_space(3))) void*)(ldst), 16, 0, 0)

// ---------------- conversion / assembly kernels ----------------

__global__ void k_cvt8(const float* __restrict__ src, unsigned short* __restrict__ dst, int n8) {
    int i = blockIdx.x * blockDim.x + threadIdx.x;
    int stride = gridDim.x * blockDim.x;
    for (; i < n8; i += stride) {
        const float4* s = (const float4*)(src + (size_t)i * 8);
        *(bf16x8*)(dst + (size_t)i * 8) = pack8(s[0], s[1]);
    }
}

// hidden (2,256,1024): h0 -> A0[:,2304:3328]; h1 -> A1[:,1024:2048]; h1 -> hid1bf contiguous
__global__ void k_hid_prep(const float* __restrict__ hidden, unsigned short* __restrict__ A0,
                           unsigned short* __restrict__ A1, unsigned short* __restrict__ h1b) {
    int i = blockIdx.x * blockDim.x + threadIdx.x;   // 32768 chunks of 8
    int n = i >> 7, e0 = (i & 127) * 8;
    const float4* p0 = (const float4*)(hidden + (size_t)n * 1024 + e0);
    const float4* p1 = (const float4*)(hidden + 262144 + (size_t)n * 1024 + e0);
    bf16x8 o0 = pack8(p0[0], p0[1]);
    bf16x8 o1 = pack8(p1[0], p1[1]);
    *(bf16x8*)(A0 + (size_t)n * 3328 + 2304 + e0) = o0;
    *(bf16x8*)(A1 + (size_t)n * 2048 + 1024 + e0) = o1;
    *(bf16x8*)(h1b + (size_t)n * 1024 + e0) = o1;
}

// fused layer-0 weights: B0 (4096 x 3328)
// rows [0,2048): [W_ih0[r] | W_hh0[r]] (r,z gates, pre-summable)
// rows [2048,3072): [W_ih0[r] | 0]  (n-gate, input part)
// rows [3072,4096): [0 | W_hh0[r-1024]] (n-gate, hidden part)
__global__ void k_makeB0(const float* __restrict__ Wih, const float* __restrict__ Whh,
                         unsigned short* __restrict__ B0) {
    int i = blockIdx.x * blockDim.x + threadIdx.x;
    const int total = 4096 * 416;                     // chunks of 8 along K=3328
    int stride = gridDim.x * blockDim.x;
    for (; i < total; i += stride) {
        int r = i / 416;
        int kc = (i - r * 416) * 8;
        const float* src = nullptr;
        if (r < 2048)      src = (kc < 2304) ? (Wih + (size_t)r * 2304 + kc)
                                             : (Whh + (size_t)r * 1024 + (kc - 2304));
        else if (r < 3072) { if (kc < 2304)  src = Wih + (size_t)r * 2304 + kc; }
        else               { if (kc >= 2304) src = Whh + (size_t)(r - 1024) * 1024 + (kc - 2304); }
        bf16x8 o;
        if (src) { const float4* s4 = (const float4*)src; o = pack8(s4[0], s4[1]); }
        else     { for (int k = 0; k < 8; ++k) o[k] = 0; }
        *(bf16x8*)(B0 + (size_t)r * 3328 + kc) = o;
    }
}

// fused layer-1 weights: B1 (4096 x 2048), K split at 1024
__global__ void k_makeB1(const float* __restrict__ Wih, const float* __restrict__ Whh,
                         unsigned short* __restrict__ B1) {
    int i = blockIdx.x * blockDim.x + threadIdx.x;
    const int total = 4096 * 256;
    int stride = gridDim.x * blockDim.x;
    for (; i < total; i += stride) {
        int r = i >> 8;
        int kc = (i & 255) * 8;
        const float* src = nullptr;
        if (r < 2048)      src = (kc < 1024) ? (Wih + (size_t)r * 1024 + kc)
                                             : (Whh + (size_t)r * 1024 + (kc - 1024));
        else if (r < 3072) { if (kc < 1024)  src = Wih + (size_t)r * 1024 + kc; }
        else               { if (kc >= 1024) src = Whh + (size_t)(r - 1024) * 1024 + (kc - 1024); }
        bf16x8 o;
        if (src) { const float4* s4 = (const float4*)src; o = pack8(s4[0], s4[1]); }
        else     { for (int k = 0; k < 8; ++k) o[k] = 0; }
        *(bf16x8*)(B1 + (size_t)r * 2048 + kc) = o;
    }
}

// ---------------- GEMM C = A(MxK) * B(NxK)^T, bf16 in, fp32 out ----------------
// 128x128 tile, 4 waves (2x2), 16x16x32 MFMA, global_load_lds staging (m97 structure).
// grid = (N/128, M/128); K % 32 == 0. Optional bias[col].

__global__ __launch_bounds__(256) void gemm_bt(
        const unsigned short* __restrict__ A, const unsigned short* __restrict__ B,
        float* __restrict__ C, const float* __restrict__ bias, int N, int K) {
    __shared__ unsigned short sA[4096];   // [128][32]
    __shared__ unsigned short sB[4096];
    const int nbx = gridDim.x;
    const int nwg = nbx * gridDim.y;
    int d = blockIdx.y * nbx + blockIdx.x;
    int f = d;
    if ((nwg & 7) == 0) { int cpx = nwg >> 3; f = (d & 7) * cpx + (d >> 3); }  // XCD chunking
    const int bx = f % nbx, by = f / nbx;
    const int t = threadIdx.x, wave = t >> 6, lane = t & 63;
    const int wm = wave >> 1, wn = wave & 1;
    const int lg = lane >> 4, r16 = lane & 15;
    const int row0 = by * 128, col0 = bx * 128;

    const int cr = t >> 2, ckc = (t & 3) * 8;
    const unsigned short* gA  = A + (size_t)(row0 + cr) * K + ckc;
    const unsigned short* gA2 = gA + (size_t)64 * K;
    const unsigned short* gB  = B + (size_t)(col0 + cr) * K + ckc;
    const unsigned short* gB2 = gB + (size_t)64 * K;
    unsigned short* lA1 = sA + wave * 512;
    unsigned short* lA2 = sA + 2048 + wave * 512;
    unsigned short* lB1 = sB + wave * 512;
    unsigned short* lB2 = sB + 2048 + wave * 512;

    f32x4 acc[4][4];
    #pragma unroll
    for (int i = 0; i < 4; ++i)
        #pragma unroll
        for (int j = 0; j < 4; ++j)
            #pragma unroll
            for (int q = 0; q < 4; ++q) acc[i][j][q] = 0.0f;

    const int ao = (wm * 64 + r16) * 32 + lg * 8;
    const int bo = (wn * 64 + r16) * 32 + lg * 8;

    for (int kt = 0; kt < K; kt += 32) {
        GLOAD_LDS16(gA, lA1); GLOAD_LDS16(gA2, lA2);
        GLOAD_LDS16(gB, lB1); GLOAD_LDS16(gB2, lB2);
        gA += 32; gA2 += 32; gB += 32; gB2 += 32;
        __syncthreads();
        bf16x8 af[4], bfr[4];
        #pragma unroll
        for (int i = 0; i < 4; ++i) af[i]  = *(const bf16x8*)(sA + ao + i * 512);
        #pragma unroll
        for (int j = 0; j < 4; ++j) bfr[j] = *(const bf16x8*)(sB + bo + j * 512);
        #pragma unroll
        for (int i = 0; i < 4; ++i)
            #pragma unroll
            for (int j = 0; j < 4; ++j)
                acc[i][j] = __builtin_amdgcn_mfma_f32_16x16x32_bf16(af[i], bfr[j], acc[i][j], 0, 0, 0);
        __syncthreads();
    }
    // C/D layout (m89-verified): col = lane&15, row = (lane>>4)*4 + reg
    #pragma unroll
    for (int i = 0; i < 4; ++i)
        #pragma unroll
        for (int j = 0; j < 4; ++j)
            #pragma unroll
            for (int q = 0; q < 4; ++q) {
                int row = row0 + wm * 64 + i * 16 + lg * 4 + q;
                int col = col0 + wn * 64 + j * 16 + r16;
                float v = acc[i][j][q];
                if (bias) v += bias[col];
                C[(size_t)row * N + col] = v;
            }
}

// u-GEMM specialized: same mainloop, epilogue folds u into energy partials.
// A = es_bf16 (16384 x 2048), B = U_w_bf16 (1024 x 2048). grid (8, 128).
// e_part[m*16 + bx*2 + wn] = sum_{cols of this wave} attn_w[h]*tanh(c + U_b[h] + w[n,h])
__global__ __launch_bounds__(256) void gemm_energy(
        const unsigned short* __restrict__ A, const unsigned short* __restrict__ B,
        const float* __restrict__ attn_w, const float* __restrict__ U_b,
        const float* __restrict__ wbuf, float* __restrict__ e_part) {
    const int K = 2048;
    __shared__ unsigned short sA[4096];
    __shared__ unsigned short sB[4096];
    const int nbx = gridDim.x;                         // 8
    const int nwg = nbx * gridDim.y;                   // 1024
    int d = blockIdx.y * nbx + blockIdx.x;
    int cpx = nwg >> 3;
    int f = (d & 7) * cpx + (d >> 3);
    const int bx = f % nbx, by = f / nbx;
    const int t = threadIdx.x, wave = t >> 6, lane = t & 63;
    const int wm = wave >> 1, wn = wave & 1;
    const int lg = lane >> 4, r16 = lane & 15;
    const int row0 = by * 128, col0 = bx * 128;

    const int cr = t >> 2, ckc = (t & 3) * 8;
    const unsigned short* gA  = A + (size_t)(row0 + cr) * K + ckc;
    const unsigned short* gA2 = gA + (size_t)64 * K;
    const unsigned short* gB  = B + (size_t)(col0 + cr) * K + ckc;
    const unsigned short* gB2 = gB + (size_t)64 * K;
    unsigned short* lA1 = sA + wave * 512;
    unsigned short* lA2 = sA + 2048 + wave * 512;
    unsigned short* lB1 = sB + wave * 512;
    unsigned short* lB2 = sB + 2048 + wave * 512;

    f32x4 acc[4][4];
    #pragma unroll
    for (int i = 0; i < 4; ++i)
        #pragma unroll
        for (int j = 0; j < 4; ++j)
            #pragma unroll
            for (int q = 0; q < 4; ++q) acc[i][j][q] = 0.0f;

    const int ao = (wm * 64 + r16) * 32 + lg * 8;
    const int bo = (wn * 64 + r16) * 32 + lg * 8;

    for (int kt = 0; kt < K; kt += 32) {
        GLOAD_LDS16(gA, lA1); GLOAD_LDS16(gA2, lA2);
        GLOAD_LDS16(gB, lB1); GLOAD_LDS16(gB2, lB2);
        gA += 32; gA2 += 32; gB += 32; gB2 += 32;
        __syncthreads();
        bf16x8 af[4], bfr[4];
        #pragma unroll
        for (int i = 0; i < 4; ++i) af[i]  = *(const bf16x8*)(sA + ao + i * 512);
        #pragma unroll
        for (int j = 0; j < 4; ++j) bfr[j] = *(const bf16x8*)(sB + bo + j * 512);
        #pragma unroll
        for (int i = 0; i < 4; ++i)
            #pragma unroll
            for (int j = 0; j < 4; ++j)
                acc[i][j] = __builtin_amdgcn_mfma_f32_16x16x32_bf16(af[i], bfr[j], acc[i][j], 0, 0, 0);
        __syncthreads();
    }
    // epilogue: energy partials, reduced over the 16 lanes of each row group
    float aw[4], ub[4];
    #pragma unroll
    for (int j = 0; j < 4; ++j) {
        int col = col0 + wn * 64 + j * 16 + r16;
        aw[j] = attn_w[col];
        ub[j] = U_b[col];
    }
    #pragma unroll
    for (int i = 0; i < 4; ++i)
        #pragma unroll
        for (int q = 0; q < 4; ++q) {
            int m = row0 + wm * 64 + i * 16 + lg * 4 + q;
            int nb = m & 255;                           // batch index (m = s*256 + n)
            const float* wrow = wbuf + (size_t)nb * 1024;
            float e = 0.f;
            #pragma unroll
            for (int j = 0; j < 4; ++j) {
                int col = col0 + wn * 64 + j * 16 + r16;
                float c = acc[i][j][q] + ub[j] + wrow[col];
                e += aw[j] * tanhf(c);
            }
            e += __shfl_xor(e, 1); e += __shfl_xor(e, 2);
            e += __shfl_xor(e, 4); e += __shfl_xor(e, 8);
            if (r16 == 0) e_part[(size_t)m * 16 + bx * 2 + wn] = e;
        }
}

// softmax over s (64) for each n (256); writes attention (S,N) fp32
__global__ __launch_bounds__(256) void k_softmax(const float* __restrict__ e_part,
                                                 float* __restrict__ attn) {
    int n = threadIdx.x;
    float e[64];
    float mx = -1e30f;
    #pragma unroll
    for (int s = 0; s < 64; ++s) {
        const float* p = e_part + ((size_t)(s * 256 + n)) * 16;
        float v = 0.f;
        #pragma unroll
        for (int k = 0; k < 16; ++k) v += p[k];
        e[s] = v; mx = fmaxf(mx, v);
    }
    float sum = 0.f;
    #pragma unroll
    for (int s = 0; s < 64; ++s) { e[s] = expf(e[s] - mx); sum += e[s]; }
    float inv = 1.0f / sum;
    #pragma unroll
    for (int s = 0; s < 64; ++s) attn[s * 256 + n] = e[s] * inv;
}

// context[n,:] = sum_s attn[s,n]*es[s,n,:]; writes bf16 into A0[:, 0:2048]; emb gather into A0[:, 2048:2304]
__global__ void k_context(const unsigned short* __restrict__ esb, const float* __restrict__ attn,
                          const float* __restrict__ emb, const int* __restrict__ x,
                          unsigned short* __restrict__ A0) {
    int n = blockIdx.x, t = threadIdx.x;
    __shared__ float as_[64];
    if (t < 64) as_[t] = attn[t * 256 + n];
    __syncthreads();
    float acc[8];
    #pragma unroll
    for (int k = 0; k < 8; ++k) acc[k] = 0.f;
    const unsigned short* base = esb + (size_t)n * 2048 + t * 8;
    for (int s = 0; s < 64; ++s) {
        bf16x8 v = *(const bf16x8*)(base + (size_t)s * 524288);
        float a = as_[s];
        #pragma unroll
        for (int k = 0; k < 8; ++k) acc[k] += a * bf2f((unsigned short)v[k]);
    }
    bf16x8 o;
    #pragma unroll
    for (int k = 0; k < 8; ++k) o[k] = (short)f2bf(acc[k]);
    *(bf16x8*)(A0 + (size_t)n * 3328 + t * 8) = o;
    if (t < 32) {
        const float* ep = emb + (size_t)x[n] * 256 + t * 8;
        const float4* e4 = (const float4*)ep;
        *(bf16x8*)(A0 + (size_t)n * 3328 + 2048 + t * 8) = pack8(e4[0], e4[1]);
    }
}

// GRU gate math from fused GEMM output g (N x 4096): [r(1024) z(1024) i_n(1024) h_n(1024)]
__global__ void k_gru(const float* __restrict__ g, const float* __restrict__ b_ih,
                      const float* __restrict__ b_hh, const float* __restrict__ h_in,
                      float* __restrict__ h_out, unsigned short* __restrict__ a_dst,
                      int dst_pitch) {
    int i = blockIdx.x * blockDim.x + threadIdx.x;   // 262144
    int n = i >> 10, e = i & 1023;
    const float* gn = g + (size_t)n * 4096;
    float rr  = gn[e]        + b_ih[e]        + b_hh[e];
    float zz  = gn[1024 + e] + b_ih[1024 + e] + b_hh[1024 + e];
    float in_ = gn[2048 + e] + b_ih[2048 + e];
    float hn_ = gn[3072 + e] + b_hh[2048 + e];
    float r = 1.f / (1.f + expf(-rr));
    float z = 1.f / (1.f + expf(-zz));
    float nn = tanhf(in_ + r * hn_);
    float h = h_in[i];
    float ho = (1.f - z) * nn + z * h;
    h_out[i] = ho;
    a_dst[(size_t)n * dst_pitch + e] = f2bf(ho);
}

// ---------------- launch ----------------

extern "C" void kernel_launch(void* const* d_in, const int* in_sizes, int n_in,
                              void* d_out, int out_size, void* d_ws, size_t ws_size,
                              hipStream_t stream) {
    const int*   x      = (const int*)  d_in[0];
    const float* es     = (const float*)d_in[1];
    const float* hidden = (const float*)d_in[2];
    // d_in[3] = cell (unused by reference)
    const float* emb    = (const float*)d_in[4];
    const float* U_w    = (const float*)d_in[5];
    const float* U_b    = (const float*)d_in[6];
    const float* W_w    = (const float*)d_in[7];
    const float* W_b    = (const float*)d_in[8];
    const float* attn_w = (const float*)d_in[9];
    // d_in[10] = attn_b (softmax-invariant, dropped)
    const float* W_ih0  = (const float*)d_in[11];
    const float* W_hh0  = (const float*)d_in[12];
    const float* b_ih0  = (const float*)d_in[13];
    const float* b_hh0  = (const float*)d_in[14];
    const float* W_ih1  = (const float*)d_in[15];
    const float* W_hh1  = (const float*)d_in[16];
    const float* b_ih1  = (const float*)d_in[17];
    const float* b_hh1  = (const float*)d_in[18];
    const float* fc_w   = (const float*)d_in[19];
    const float* fc_b   = (const float*)d_in[20];

    float* out        = (float*)d_out;
    float* out_pred   = out;                       // 256*128
    float* out_hidden = out + 32768;               // 2*256*1024
    float* out_attn   = out + 32768 + 524288;      // 64*256

    char* ws = (char*)d_ws;
    size_t off = 0;
    auto alloc = [&](size_t bytes) { char* p = ws + off; off += (bytes + 255) & ~(size_t)255; return p; };
    unsigned short* ES_BF  = (unsigned short*)alloc((size_t)16384 * 2048 * 2);
    unsigned short* UW_BF  = (unsigned short*)alloc((size_t)1024 * 2048 * 2);
    unsigned short* WW_BF  = (unsigned short*)alloc((size_t)1024 * 1024 * 2);
    unsigned short* FCW_BF = (unsigned short*)alloc((size_t)128 * 1024 * 2);
    unsigned short* H1_BF  = (unsigned short*)alloc((size_t)256 * 1024 * 2);
    unsigned short* B0     = (unsigned short*)alloc((size_t)4096 * 3328 * 2);
    unsigned short* B1     = (unsigned short*)alloc((size_t)4096 * 2048 * 2);
    unsigned short* A0     = (unsigned short*)alloc((size_t)256 * 3328 * 2);
    unsigned short* A1     = (unsigned short*)alloc((size_t)256 * 2048 * 2);
    unsigned short* FCA    = (unsigned short*)alloc((size_t)256 * 1024 * 2);
    float* WBUF  = (float*)alloc((size_t)256 * 1024 * 4);
    float* EPART = (float*)alloc((size_t)16384 * 16 * 4);
    float* G0    = (float*)alloc((size_t)256 * 4096 * 4);
    float* G1    = (float*)alloc((size_t)256 * 4096 * 4);

    // conversions & weight assembly
    k_cvt8<<<2048, 256, 0, stream>>>(es,   ES_BF,  4194304);
    k_cvt8<<<512,  256, 0, stream>>>(U_w,  UW_BF,  262144);
    k_cvt8<<<256,  256, 0, stream>>>(W_w,  WW_BF,  131072);
    k_cvt8<<<64,   256, 0, stream>>>(fc_w, FCW_BF, 16384);
    k_hid_prep<<<128, 256, 0, stream>>>(hidden, A0, A1, H1_BF);
    k_makeB0<<<2048, 256, 0, stream>>>(W_ih0, W_hh0, B0);
    k_makeB1<<<2048, 256, 0, stream>>>(W_ih1, W_hh1, B1);

    // w = hidden[1] @ W_w^T + W_b
    gemm_bt<<<dim3(8, 2), 256, 0, stream>>>(H1_BF, WW_BF, WBUF, W_b, 1024, 1024);
    // u-GEMM + fused energy epilogue
    gemm_energy<<<dim3(8, 128), 256, 0, stream>>>(ES_BF, UW_BF, attn_w, U_b, WBUF, EPART);
    // attention softmax (writes output region)
    k_softmax<<<1, 256, 0, stream>>>(EPART, out_attn);
    // context + embedding -> A0
    k_context<<<256, 256, 0, stream>>>(ES_BF, out_attn, emb, x, A0);
    // GRU layer 0
    gemm_bt<<<dim3(32, 2), 256, 0, stream>>>(A0, B0, G0, nullptr, 4096, 3328);
    k_gru<<<1024, 256, 0, stream>>>(G0, b_ih0, b_hh0, hidden, out_hidden, A1, 2048);
    // GRU layer 1
    gemm_bt<<<dim3(32, 2), 256, 0, stream>>>(A1, B1, G1, nullptr, 4096, 2048);
    k_gru<<<1024, 256, 0, stream>>>(G1, b_ih1, b_hh1, hidden + 262144, out_hidden + 262144, FCA, 1024);
    // predictions = h1 @ fc_w^T + fc_b
    gemm_bt<<<dim3(1, 2), 256, 0, stream>>>(FCA, FCW_BF, out_pred, fc_b, 128, 1024);
}

// Round 2
// 329.366 us; speedup vs baseline: 1.2610x; 1.2610x over previous
//
#include <hip/hip_runtime.h>
#include <stdint.h>

typedef __attribute__((ext_vector_type(8))) short bf16x8;   // 8 bf16 = 4 VGPRs
typedef __attribute__((ext_vector_type(4))) float f32x4;

#define DEVI __device__ __forceinline__

DEVI unsigned short f2bf(float f) {
    union { float f; uint32_t u; } v; v.f = f;
    uint32_t r = v.u + 0x7FFFu + ((v.u >> 16) & 1u);   // RNE
    return (unsigned short)(r >> 16);
}
DEVI float bf2f(unsigned short h) {
    union { uint32_t u; float f; } v; v.u = ((uint32_t)h) << 16;
    return v.f;
}
DEVI bf16x8 pack8(float4 a, float4 b) {
    bf16x8 o;
    o[0]=(short)f2bf(a.x); o[1]=(short)f2bf(a.y); o[2]=(short)f2bf(a.z); o[3]=(short)f2bf(a.w);
    o[4]=(short)f2bf(b.x); o[5]=(short)f2bf(b.y); o[6]=(short)f2bf(b.z); o[7]=(short)f2bf(b.w);
    return o;
}

#define GLOAD_LDS16(gsrc, ldst) \
    __builtin_amdgcn_global_load_lds((__attribute__((address_space(1))) void*)(gsrc), \
                                     (__attribute__((address_space(3))) void*)(ldst), 16, 0, 0)

#define BARR asm volatile("s_barrier" ::: "memory")
#define WAITV(n) asm volatile("s_waitcnt vmcnt(" #n ")" ::: "memory")

// ---------------- fused prep: all fp32->bf16 conversions + GRU weight assembly ----------------
// segment chunk offsets (8-elem chunks):
//  [0, 4194304)            es -> ES_BF
//  [.., +262144)           U_w -> UW_BF
//  [.., +131072)           W_w -> WW_BF
//  [.., +16384)            fc_w -> FCW_BF
//  [.., +32768)            hidden -> A0[:,2304:], A1[:,1024:], H1_BF
//  [.., +1703936)          B0 assembly (4096 x 3328)
//  [.., +1048576)          B1 assembly (4096 x 2048)
__global__ void k_prep(const float* __restrict__ es, const float* __restrict__ U_w,
                       const float* __restrict__ W_w, const float* __restrict__ fc_w,
                       const float* __restrict__ hidden,
                       const float* __restrict__ Wih0, const float* __restrict__ Whh0,
                       const float* __restrict__ Wih1, const float* __restrict__ Whh1,
                       unsigned short* __restrict__ ES_BF, unsigned short* __restrict__ UW_BF,
                       unsigned short* __restrict__ WW_BF, unsigned short* __restrict__ FCW_BF,
                       unsigned short* __restrict__ A0, unsigned short* __restrict__ A1,
                       unsigned short* __restrict__ H1B,
                       unsigned short* __restrict__ B0, unsigned short* __restrict__ B1) {
    int i = blockIdx.x * blockDim.x + threadIdx.x;
    const int S0 = 4194304, S1 = S0 + 262144, S2 = S1 + 131072, S3 = S2 + 16384;
    const int S4 = S3 + 32768, S5 = S4 + 1703936, S6 = S5 + 1048576;
    if (i < S0) {
        const float4* s = (const float4*)(es + (size_t)i * 8);
        *(bf16x8*)(ES_BF + (size_t)i * 8) = pack8(s[0], s[1]);
    } else if (i < S1) {
        int j = i - S0;
        const float4* s = (const float4*)(U_w + (size_t)j * 8);
        *(bf16x8*)(UW_BF + (size_t)j * 8) = pack8(s[0], s[1]);
    } else if (i < S2) {
        int j = i - S1;
        const float4* s = (const float4*)(W_w + (size_t)j * 8);
        *(bf16x8*)(WW_BF + (size_t)j * 8) = pack8(s[0], s[1]);
    } else if (i < S3) {
        int j = i - S2;
        const float4* s = (const float4*)(fc_w + (size_t)j * 8);
        *(bf16x8*)(FCW_BF + (size_t)j * 8) = pack8(s[0], s[1]);
    } else if (i < S4) {
        int j = i - S3;
        int n = j >> 7, e0 = (j & 127) * 8;
        const float4* p0 = (const float4*)(hidden + (size_t)n * 1024 + e0);
        const float4* p1 = (const float4*)(hidden + 262144 + (size_t)n * 1024 + e0);
        bf16x8 o0 = pack8(p0[0], p0[1]);
        bf16x8 o1 = pack8(p1[0], p1[1]);
        *(bf16x8*)(A0 + (size_t)n * 3328 + 2304 + e0) = o0;
        *(bf16x8*)(A1 + (size_t)n * 2048 + 1024 + e0) = o1;
        *(bf16x8*)(H1B + (size_t)n * 1024 + e0) = o1;
    } else if (i < S5) {
        unsigned j = (unsigned)(i - S4);
        unsigned r = j / 416u;
        int kc = (int)(j - r * 416u) * 8;
        const float* src = nullptr;
        if (r < 2048)      src = (kc < 2304) ? (Wih0 + (size_t)r * 2304 + kc)
                                             : (Whh0 + (size_t)r * 1024 + (kc - 2304));
        else if (r < 3072) { if (kc < 2304)  src = Wih0 + (size_t)r * 2304 + kc; }
        else               { if (kc >= 2304) src = Whh0 + (size_t)(r - 1024) * 1024 + (kc - 2304); }
        bf16x8 o;
        if (src) { const float4* s4 = (const float4*)src; o = pack8(s4[0], s4[1]); }
        else     { for (int k = 0; k < 8; ++k) o[k] = 0; }
        *(bf16x8*)(B0 + (size_t)r * 3328 + kc) = o;
    } else if (i < S6) {
        int j = i - S5;
        int r = j >> 8;
        int kc = (j & 255) * 8;
        const float* src = nullptr;
        if (r < 2048)      src = (kc < 1024) ? (Wih1 + (size_t)r * 1024 + kc)
                                             : (Whh1 + (size_t)r * 1024 + (kc - 1024));
        else if (r < 3072) { if (kc < 1024)  src = Wih1 + (size_t)r * 1024 + kc; }
        else               { if (kc >= 1024) src = Whh1 + (size_t)(r - 1024) * 1024 + (kc - 1024); }
        bf16x8 o;
        if (src) { const float4* s4 = (const float4*)src; o = pack8(s4[0], s4[1]); }
        else     { for (int k = 0; k < 8; ++k) o[k] = 0; }
        *(bf16x8*)(B1 + (size_t)r * 2048 + kc) = o;
    }
}

// ---------------- small GEMM C = A(MxK) * B(NxK)^T (m97 128^2 structure, kept for GRU/fc/w) ---
__global__ __launch_bounds__(256) void gemm_bt(
        const unsigned short* __restrict__ A, const unsigned short* __restrict__ B,
        float* __restrict__ C, const float* __restrict__ bias, int N, int K) {
    __shared__ unsigned short sA[4096];
    __shared__ unsigned short sB[4096];
    const int nbx = gridDim.x;
    const int nwg = nbx * gridDim.y;
    int d = blockIdx.y * nbx + blockIdx.x;
    int f = d;
    if ((nwg & 7) == 0) { int cpx = nwg >> 3; f = (d & 7) * cpx + (d >> 3); }
    const int bx = f % nbx, by = f / nbx;
    const int t = threadIdx.x, wave = t >> 6, lane = t & 63;
    const int wm = wave >> 1, wn = wave & 1;
    const int lg = lane >> 4, r16 = lane & 15;
    const int row0 = by * 128, col0 = bx * 128;

    const int cr = t >> 2, ckc = (t & 3) * 8;
    const unsigned short* gA  = A + (size_t)(row0 + cr) * K + ckc;
    const unsigned short* gA2 = gA + (size_t)64 * K;
    const unsigned short* gB  = B + (size_t)(col0 + cr) * K + ckc;
    const unsigned short* gB2 = gB + (size_t)64 * K;
    unsigned short* lA1 = sA + wave * 512;
    unsigned short* lA2 = sA + 2048 + wave * 512;
    unsigned short* lB1 = sB + wave * 512;
    unsigned short* lB2 = sB + 2048 + wave * 512;

    f32x4 acc[4][4];
    #pragma unroll
    for (int i = 0; i < 4; ++i)
        #pragma unroll
        for (int j = 0; j < 4; ++j)
            #pragma unroll
            for (int q = 0; q < 4; ++q) acc[i][j][q] = 0.0f;

    const int ao = (wm * 64 + r16) * 32 + lg * 8;
    const int bo = (wn * 64 + r16) * 32 + lg * 8;

    for (int kt = 0; kt < K; kt += 32) {
        GLOAD_LDS16(gA, lA1); GLOAD_LDS16(gA2, lA2);
        GLOAD_LDS16(gB, lB1); GLOAD_LDS16(gB2, lB2);
        gA += 32; gA2 += 32; gB += 32; gB2 += 32;
        __syncthreads();
        bf16x8 af[4], bfr[4];
        #pragma unroll
        for (int i = 0; i < 4; ++i) af[i]  = *(const bf16x8*)(sA + ao + i * 512);
        #pragma unroll
        for (int j = 0; j < 4; ++j) bfr[j] = *(const bf16x8*)(sB + bo + j * 512);
        #pragma unroll
        for (int i = 0; i < 4; ++i)
            #pragma unroll
            for (int j = 0; j < 4; ++j)
                acc[i][j] = __builtin_amdgcn_mfma_f32_16x16x32_bf16(af[i], bfr[j], acc[i][j], 0, 0, 0);
        __syncthreads();
    }
    #pragma unroll
    for (int i = 0; i < 4; ++i)
        #pragma unroll
        for (int j = 0; j < 4; ++j)
            #pragma unroll
            for (int q = 0; q < 4; ++q) {
                int row = row0 + wm * 64 + i * 16 + lg * 4 + q;
                int col = col0 + wn * 64 + j * 16 + r16;
                float v = acc[i][j][q];
                if (bias) v += bias[col];
                C[(size_t)row * N + col] = v;
            }
}

// ---------------- 256^2 8-phase u-GEMM with fused energy epilogue ----------------
// A = es_bf16 (16384 x 2048) row-major; B = U_w_bf16 (1024 x 2048) row-major (B^T GEMM).
// Tile 256x256, BK=64, 8 waves (2M x 4N), per-wave C: 128 x 64.
// LDS: 2 tile-slots x {A: 2 halves x 16KB, B: 2 halves x 16KB} = 128 KiB.
// T2 swizzle: element (r,k) of a [128][64] half at byte r*128 + ((k>>3)^(r&7))*16 + (k&7)*2.
//   gload_lds writes linearly -> per-lane global source pre-permuted with the same XOR.
// Counted-vmcnt pipeline: issue tile t+1's 8 loads, then vmcnt(8) waits only tile t.
__global__ __launch_bounds__(512, 2) void gemm_energy256(
        const unsigned short* __restrict__ A, const unsigned short* __restrict__ B,
        const float* __restrict__ attn_w, const float* __restrict__ U_b,
        const float* __restrict__ wbuf, float* __restrict__ e_part) {
    const int NT = 2048 / 64;                       // 32 K-tiles
    __shared__ __align__(16) unsigned short lds[65536];   // 128 KiB

    const int t = threadIdx.x;
    const int w = t >> 6, lane = t & 63;
    const int wm = w >> 2, wn = w & 3;
    const int lg = lane >> 4, r16 = lane & 15;

    int d = blockIdx.y * gridDim.x + blockIdx.x;    // grid (4, 64) = 256 blocks
    int f = (d & 7) * 32 + (d >> 3);                // bijective XCD swizzle (256 % 8 == 0)
    const int bx = f & 3, by = f >> 2;
    const int row0 = by * 256, col0 = bx * 256;

    // staging: 64 chunks of 1KB (8 rows of a [128][64] half); chunk c = q*8 + w
    // c: mat = c>>5 (0=A,1=B), half = (c>>4)&1, rowgrp = c&15
    // lane l: row_in_half = rowgrp*8 + (l>>3); src slot = (l&7)^(l>>3)  [XOR-swizzle involution]
    const unsigned short* gbase[8];
    unsigned lbase[8];
    #pragma unroll
    for (int q = 0; q < 8; ++q) {
        int c = q * 8 + w;
        int mat = c >> 5, half = (c >> 4) & 1, rg = c & 15;
        int rih = rg * 8 + (lane >> 3);
        int slot = (lane & 7) ^ (lane >> 3);
        gbase[q] = (mat == 0)
            ? A + (size_t)(row0 + half * 128 + rih) * 2048 + slot * 8
            : B + (size_t)(col0 + half * 128 + rih) * 2048 + slot * 8;
        lbase[q] = (unsigned)(mat * 32768 + half * 16384 + rg * 1024);
    }

#define STAGE(T, cbuf) do { \
    char* lp_ = (char*)lds + (cbuf) * 65536; \
    _Pragma("unroll") \
    for (int q_ = 0; q_ < 8; ++q_) \
        GLOAD_LDS16(gbase[q_] + (size_t)(T) * 64, lp_ + lbase[q_]); \
} while (0)

    // ds_read byte offsets (within a tile-slot). kk toggles byte bit 6 (slot XOR 4).
    const unsigned swz = (unsigned)((lg ^ (r16 & 7)) * 16);
    const unsigned aoff0 = (unsigned)(wm * 16384 + r16 * 128) + swz;
    const unsigned boff0 = (unsigned)(32768 + (wn >> 1) * 16384 + ((wn & 1) * 64 + r16) * 128) + swz;

    f32x4 acc[8][4];
    #pragma unroll
    for (int m = 0; m < 8; ++m)
        #pragma unroll
        for (int n = 0; n < 4; ++n)
            #pragma unroll
            for (int q = 0; q < 4; ++q) acc[m][n][q] = 0.0f;

// one K-tile: 4 phases (kk x mh), each {ds_read 4-8, barrier, setprio, 16 MFMA, setprio, barrier}
#define KTILE(cbuf) do { \
    const char* lp_ = (const char*)lds + (cbuf) * 65536; \
    _Pragma("unroll") \
    for (int kk_ = 0; kk_ < 2; ++kk_) { \
        bf16x8 bf_[4]; \
        _Pragma("unroll") \
        for (int n_ = 0; n_ < 4; ++n_) \
            bf_[n_] = *(const bf16x8*)(lp_ + ((boff0 + n_ * 2048) ^ (kk_ << 6))); \
        _Pragma("unroll") \
        for (int mh_ = 0; mh_ < 2; ++mh_) { \
            bf16x8 af_[4]; \
            _Pragma("unroll") \
            for (int mm_ = 0; mm_ < 4; ++mm_) \
                af_[mm_] = *(const bf16x8*)(lp_ + ((aoff0 + (mh_ * 4 + mm_) * 2048) ^ (kk_ << 6))); \
            BARR; \
            __builtin_amdgcn_s_setprio(1); \
            _Pragma("unroll") \
            for (int mm_ = 0; mm_ < 4; ++mm_) \
                _Pragma("unroll") \
                for (int n_ = 0; n_ < 4; ++n_) \
                    acc[mh_ * 4 + mm_][n_] = __builtin_amdgcn_mfma_f32_16x16x32_bf16( \
                        af_[mm_], bf_[n_], acc[mh_ * 4 + mm_][n_], 0, 0, 0); \
            __builtin_amdgcn_s_setprio(0); \
            BARR; \
        } \
    } \
} while (0)

    STAGE(0, 0);
    for (int it = 0; it < NT / 2; ++it) {
        STAGE(2 * it + 1, 1);          // buf1 free (trailing barrier of prev KTILE(1))
        WAITV(8);                      // tile 2it landed (its 8 loads are oldest)
        BARR;
        KTILE(0);                      // consume tile 2it; trailing barrier frees buf0
        if (2 * it + 2 < NT) {
            STAGE(2 * it + 2, 0);
            WAITV(8);                  // tile 2it+1 landed
        } else {
            WAITV(0);
        }
        BARR;
        KTILE(1);                      // consume tile 2it+1; trailing barrier frees buf1
    }
#undef STAGE
#undef KTILE

    // fused energy epilogue: e_part[row*16 + bx*4 + wn] = sum_cols aw*tanh(acc + U_b + w[n,col])
    float aw[4], ub[4];
    #pragma unroll
    for (int n = 0; n < 4; ++n) {
        int col = col0 + wn * 64 + n * 16 + r16;
        aw[n] = attn_w[col];
        ub[n] = U_b[col];
    }
    #pragma unroll
    for (int m = 0; m < 8; ++m)
        #pragma unroll
        for (int q = 0; q < 4; ++q) {
            int lrow = wm * 128 + m * 16 + lg * 4 + q;    // local row = batch index (block = one s)
            const float* wrow = wbuf + (size_t)lrow * 1024;
            float e = 0.f;
            #pragma unroll
            for (int n = 0; n < 4; ++n) {
                int col = col0 + wn * 64 + n * 16 + r16;
                float cc = acc[m][n][q] + ub[n] + wrow[col];
                float ex = __expf(2.f * cc);               // tanh(x) = 1 - 2/(e^2x + 1)
                e += aw[n] * (1.f - 2.f / (ex + 1.f));
            }
            e += __shfl_xor(e, 1); e += __shfl_xor(e, 2);
            e += __shfl_xor(e, 4); e += __shfl_xor(e, 8);
            if (r16 == 0) e_part[(size_t)(row0 + lrow) * 16 + bx * 4 + wn] = e;
        }
}

// softmax over s (64 lanes) per n; one wave per n, 4 waves/block, 64 blocks
__global__ __launch_bounds__(256) void k_softmax2(const float* __restrict__ e_part,
                                                  float* __restrict__ attn) {
    int w = threadIdx.x >> 6, s = threadIdx.x & 63;
    int n = blockIdx.x * 4 + w;
    const float* p = e_part + ((size_t)(s * 256 + n)) * 16;
    float v = 0.f;
    #pragma unroll
    for (int k = 0; k < 16; ++k) v += p[k];
    float mx = v;
    #pragma unroll
    for (int o = 1; o < 64; o <<= 1) mx = fmaxf(mx, __shfl_xor(mx, o));
    float e = __expf(v - mx);
    float sum = e;
    #pragma unroll
    for (int o = 1; o < 64; o <<= 1) sum += __shfl_xor(sum, o);
    attn[s * 256 + n] = e / sum;
}

// context[n,:] = sum_s attn[s,n]*es[s,n,:] -> A0[:,0:2048]; emb gather -> A0[:,2048:2304]
__global__ void k_context(const unsigned short* __restrict__ esb, const float* __restrict__ attn,
                          const float* __restrict__ emb, const int* __restrict__ x,
                          unsigned short* __restrict__ A0) {
    int n = blockIdx.x, t = threadIdx.x;
    __shared__ float as_[64];
    if (t < 64) as_[t] = attn[t * 256 + n];
    __syncthreads();
    float acc[8];
    #pragma unroll
    for (int k = 0; k < 8; ++k) acc[k] = 0.f;
    const unsigned short* base = esb + (size_t)n * 2048 + t * 8;
    for (int s = 0; s < 64; ++s) {
        bf16x8 v = *(const bf16x8*)(base + (size_t)s * 524288);
        float a = as_[s];
        #pragma unroll
        for (int k = 0; k < 8; ++k) acc[k] += a * bf2f((unsigned short)v[k]);
    }
    bf16x8 o;
    #pragma unroll
    for (int k = 0; k < 8; ++k) o[k] = (short)f2bf(acc[k]);
    *(bf16x8*)(A0 + (size_t)n * 3328 + t * 8) = o;
    if (t < 32) {
        const float4* e4 = (const float4*)(emb + (size_t)x[n] * 256 + t * 8);
        *(bf16x8*)(A0 + (size_t)n * 3328 + 2048 + t * 8) = pack8(e4[0], e4[1]);
    }
}

// GRU gate math from fused GEMM output g (N x 4096): [r | z | i_n | h_n]
__global__ void k_gru(const float* __restrict__ g, const float* __restrict__ b_ih,
                      const float* __restrict__ b_hh, const float* __restrict__ h_in,
                      float* __restrict__ h_out, unsigned short* __restrict__ a_dst,
                      int dst_pitch) {
    int i = blockIdx.x * blockDim.x + threadIdx.x;   // 262144
    int n = i >> 10, e = i & 1023;
    const float* gn = g + (size_t)n * 4096;
    float rr  = gn[e]        + b_ih[e]        + b_hh[e];
    float zz  = gn[1024 + e] + b_ih[1024 + e] + b_hh[1024 + e];
    float in_ = gn[2048 + e] + b_ih[2048 + e];
    float hn_ = gn[3072 + e] + b_hh[2048 + e];
    float r = 1.f / (1.f + __expf(-rr));
    float z = 1.f / (1.f + __expf(-zz));
    float ex = __expf(2.f * (in_ + r * hn_));
    float nn = 1.f - 2.f / (ex + 1.f);
    float h = h_in[i];
    float ho = (1.f - z) * nn + z * h;
    h_out[i] = ho;
    a_dst[(size_t)n * dst_pitch + e] = f2bf(ho);
}

// ---------------- launch ----------------

extern "C" void kernel_launch(void* const* d_in, const int* in_sizes, int n_in,
                              void* d_out, int out_size, void* d_ws, size_t ws_size,
                              hipStream_t stream) {
    const int*   x      = (const int*)  d_in[0];
    const float* es     = (const float*)d_in[1];
    const float* hidden = (const float*)d_in[2];
    const float* emb    = (const float*)d_in[4];
    const float* U_w    = (const float*)d_in[5];
    const float* U_b    = (const float*)d_in[6];
    const float* W_w    = (const float*)d_in[7];
    const float* W_b    = (const float*)d_in[8];
    const float* attn_w = (const float*)d_in[9];
    const float* W_ih0  = (const float*)d_in[11];
    const float* W_hh0  = (const float*)d_in[12];
    const float* b_ih0  = (const float*)d_in[13];
    const float* b_hh0  = (const float*)d_in[14];
    const float* W_ih1  = (const float*)d_in[15];
    const float* W_hh1  = (const float*)d_in[16];
    const float* b_ih1  = (const float*)d_in[17];
    const float* b_hh1  = (const float*)d_in[18];
    const float* fc_w   = (const float*)d_in[19];
    const float* fc_b   = (const float*)d_in[20];

    float* out        = (float*)d_out;
    float* out_pred   = out;
    float* out_hidden = out + 32768;
    float* out_attn   = out + 32768 + 524288;

    char* ws = (char*)d_ws;
    size_t off = 0;
    auto alloc = [&](size_t bytes) { char* p = ws + off; off += (bytes + 255) & ~(size_t)255; return p; };
    unsigned short* ES_BF  = (unsigned short*)alloc((size_t)16384 * 2048 * 2);
    unsigned short* UW_BF  = (unsigned short*)alloc((size_t)1024 * 2048 * 2);
    unsigned short* WW_BF  = (unsigned short*)alloc((size_t)1024 * 1024 * 2);
    unsigned short* FCW_BF = (unsigned short*)alloc((size_t)128 * 1024 * 2);
    unsigned short* H1_BF  = (unsigned short*)alloc((size_t)256 * 1024 * 2);
    unsigned short* B0     = (unsigned short*)alloc((size_t)4096 * 3328 * 2);
    unsigned short* B1     = (unsigned short*)alloc((size_t)4096 * 2048 * 2);
    unsigned short* A0     = (unsigned short*)alloc((size_t)256 * 3328 * 2);
    unsigned short* A1     = (unsigned short*)alloc((size_t)256 * 2048 * 2);
    unsigned short* FCA    = (unsigned short*)alloc((size_t)256 * 1024 * 2);
    float* WBUF  = (float*)alloc((size_t)256 * 1024 * 4);
    float* EPART = (float*)alloc((size_t)16384 * 16 * 4);
    float* G0    = (float*)alloc((size_t)256 * 4096 * 4);
    float* G1    = (float*)alloc((size_t)256 * 4096 * 4);

    // one fused prep kernel (7,389,184 chunks of 8 elements = 28864 blocks x 256)
    k_prep<<<28864, 256, 0, stream>>>(es, U_w, W_w, fc_w, hidden, W_ih0, W_hh0, W_ih1, W_hh1,
                                      ES_BF, UW_BF, WW_BF, FCW_BF, A0, A1, H1_BF, B0, B1);
    // w = hidden[1] @ W_w^T + W_b
    gemm_bt<<<dim3(8, 2), 256, 0, stream>>>(H1_BF, WW_BF, WBUF, W_b, 1024, 1024);
    // u-GEMM (256^2 8-phase) + fused energy epilogue
    gemm_energy256<<<dim3(4, 64), 512, 0, stream>>>(ES_BF, UW_BF, attn_w, U_b, WBUF, EPART);
    // attention softmax
    k_softmax2<<<64, 256, 0, stream>>>(EPART, out_attn);
    // context + embedding -> A0
    k_context<<<256, 256, 0, stream>>>(ES_BF, out_attn, emb, x, A0);
    // GRU layer 0
    gemm_bt<<<dim3(32, 2), 256, 0, stream>>>(A0, B0, G0, nullptr, 4096, 3328);
    k_gru<<<1024, 256, 0, stream>>>(G0, b_ih0, b_hh0, hidden, out_hidden, A1, 2048);
    // GRU layer 1
    gemm_bt<<<dim3(32, 2), 256, 0, stream>>>(A1, B1, G1, nullptr, 4096, 2048);
    k_gru<<<1024, 256, 0, stream>>>(G1, b_ih1, b_hh1, hidden + 262144, out_hidden + 262144, FCA, 1024);
    // predictions = h1 @ fc_w^T + fc_b
    gemm_bt<<<dim3(1, 2), 256, 0, stream>>>(FCA, FCW_BF, out_pred, fc_b, 128, 1024);
}

// Round 3
// 212.884 us; speedup vs baseline: 1.9510x; 1.5472x over previous
//
#include <hip/hip_runtime.h>
#include <stdint.h>

typedef __attribute__((ext_vector_type(8))) short bf16x8;   // 8 bf16 = 4 VGPRs
typedef __attribute__((ext_vector_type(4))) float f32x4;

#define DEVI __device__ __forceinline__

DEVI unsigned short f2bf(float f) {
    union { float f; uint32_t u; } v; v.f = f;
    uint32_t r = v.u + 0x7FFFu + ((v.u >> 16) & 1u);   // RNE
    return (unsigned short)(r >> 16);
}
DEVI float bf2f(unsigned short h) {
    union { uint32_t u; float f; } v; v.u = ((uint32_t)h) << 16;
    return v.f;
}
DEVI bf16x8 pack8(float4 a, float4 b) {
    bf16x8 o;
    o[0]=(short)f2bf(a.x); o[1]=(short)f2bf(a.y); o[2]=(short)f2bf(a.z); o[3]=(short)f2bf(a.w);
    o[4]=(short)f2bf(b.x); o[5]=(short)f2bf(b.y); o[6]=(short)f2bf(b.z); o[7]=(short)f2bf(b.w);
    return o;
}

#define GLOAD_LDS16(gsrc, ldst) \
    __builtin_amdgcn_global_load_lds((__attribute__((address_space(1))) void*)(gsrc), \
                                     (__attribute__((address_space(3))) void*)(ldst), 16, 0, 0)

#define BARR asm volatile("s_barrier" ::: "memory")
#define WAITV(n) asm volatile("s_waitcnt vmcnt(" #n ")" ::: "memory")

// ---------------- fused prep: all fp32->bf16 conversions + GRU weight assembly ----------------
__global__ void k_prep(const float* __restrict__ es, const float* __restrict__ U_w,
                       const float* __restrict__ W_w, const float* __restrict__ fc_w,
                       const float* __restrict__ hidden,
                       const float* __restrict__ Wih0, const float* __restrict__ Whh0,
                       const float* __restrict__ Wih1, const float* __restrict__ Whh1,
                       unsigned short* __restrict__ ES_BF, unsigned short* __restrict__ UW_BF,
                       unsigned short* __restrict__ WW_BF, unsigned short* __restrict__ FCW_BF,
                       unsigned short* __restrict__ A0, unsigned short* __restrict__ A1,
                       unsigned short* __restrict__ H1B,
                       unsigned short* __restrict__ B0, unsigned short* __restrict__ B1) {
    int i = blockIdx.x * blockDim.x + threadIdx.x;
    const int S0 = 4194304, S1 = S0 + 262144, S2 = S1 + 131072, S3 = S2 + 16384;
    const int S4 = S3 + 32768, S5 = S4 + 1703936, S6 = S5 + 1048576;
    if (i < S0) {
        const float4* s = (const float4*)(es + (size_t)i * 8);
        *(bf16x8*)(ES_BF + (size_t)i * 8) = pack8(s[0], s[1]);
    } else if (i < S1) {
        int j = i - S0;
        const float4* s = (const float4*)(U_w + (size_t)j * 8);
        *(bf16x8*)(UW_BF + (size_t)j * 8) = pack8(s[0], s[1]);
    } else if (i < S2) {
        int j = i - S1;
        const float4* s = (const float4*)(W_w + (size_t)j * 8);
        *(bf16x8*)(WW_BF + (size_t)j * 8) = pack8(s[0], s[1]);
    } else if (i < S3) {
        int j = i - S2;
        const float4* s = (const float4*)(fc_w + (size_t)j * 8);
        *(bf16x8*)(FCW_BF + (size_t)j * 8) = pack8(s[0], s[1]);
    } else if (i < S4) {
        int j = i - S3;
        int n = j >> 7, e0 = (j & 127) * 8;
        const float4* p0 = (const float4*)(hidden + (size_t)n * 1024 + e0);
        const float4* p1 = (const float4*)(hidden + 262144 + (size_t)n * 1024 + e0);
        bf16x8 o0 = pack8(p0[0], p0[1]);
        bf16x8 o1 = pack8(p1[0], p1[1]);
        *(bf16x8*)(A0 + (size_t)n * 3328 + 2304 + e0) = o0;
        *(bf16x8*)(A1 + (size_t)n * 2048 + 1024 + e0) = o1;
        *(bf16x8*)(H1B + (size_t)n * 1024 + e0) = o1;
    } else if (i < S5) {
        unsigned j = (unsigned)(i - S4);
        unsigned r = j / 416u;
        int kc = (int)(j - r * 416u) * 8;
        const float* src = nullptr;
        if (r < 2048)      src = (kc < 2304) ? (Wih0 + (size_t)r * 2304 + kc)
                                             : (Whh0 + (size_t)r * 1024 + (kc - 2304));
        else if (r < 3072) { if (kc < 2304)  src = Wih0 + (size_t)r * 2304 + kc; }
        else               { if (kc >= 2304) src = Whh0 + (size_t)(r - 1024) * 1024 + (kc - 2304); }
        bf16x8 o;
        if (src) { const float4* s4 = (const float4*)src; o = pack8(s4[0], s4[1]); }
        else     { for (int k = 0; k < 8; ++k) o[k] = 0; }
        *(bf16x8*)(B0 + (size_t)r * 3328 + kc) = o;
    } else if (i < S6) {
        int j = i - S5;
        int r = j >> 8;
        int kc = (j & 255) * 8;
        const float* src = nullptr;
        if (r < 2048)      src = (kc < 1024) ? (Wih1 + (size_t)r * 1024 + kc)
                                             : (Whh1 + (size_t)r * 1024 + (kc - 1024));
        else if (r < 3072) { if (kc < 1024)  src = Wih1 + (size_t)r * 1024 + kc; }
        else               { if (kc >= 1024) src = Whh1 + (size_t)(r - 1024) * 1024 + (kc - 1024); }
        bf16x8 o;
        if (src) { const float4* s4 = (const float4*)src; o = pack8(s4[0], s4[1]); }
        else     { for (int k = 0; k < 8; ++k) o[k] = 0; }
        *(bf16x8*)(B1 + (size_t)r * 2048 + kc) = o;
    }
}

// ---------------- split-K GEMM: Cpart[z] = A(MxK[slice z]) * B(NxK)^T ----------------
// grid (N/128, M/128, Z). Partials summed by consumers (no bias here).
__global__ __launch_bounds__(256) void gemm_bt_sk(
        const unsigned short* __restrict__ A, const unsigned short* __restrict__ B,
        float* __restrict__ Cpart, int N, int K, int ksl) {
    __shared__ unsigned short sA[4096];
    __shared__ unsigned short sB[4096];
    const int nbx = gridDim.x;
    const int nwg = nbx * gridDim.y;
    int d = blockIdx.y * nbx + blockIdx.x;
    int f = d;
    if ((nwg & 7) == 0) { int cpx = nwg >> 3; f = (d & 7) * cpx + (d >> 3); }
    const int bx = f % nbx, by = f / nbx;
    const int z = blockIdx.z;
    const int t = threadIdx.x, wave = t >> 6, lane = t & 63;
    const int wm = wave >> 1, wn = wave & 1;
    const int lg = lane >> 4, r16 = lane & 15;
    const int row0 = by * 128, col0 = bx * 128;
    const int M = gridDim.y * 128;

    const int cr = t >> 2, ckc = (t & 3) * 8;
    const unsigned short* gA  = A + (size_t)(row0 + cr) * K + (size_t)z * ksl + ckc;
    const unsigned short* gA2 = gA + (size_t)64 * K;
    const unsigned short* gB  = B + (size_t)(col0 + cr) * K + (size_t)z * ksl + ckc;
    const unsigned short* gB2 = gB + (size_t)64 * K;
    unsigned short* lA1 = sA + wave * 512;
    unsigned short* lA2 = sA + 2048 + wave * 512;
    unsigned short* lB1 = sB + wave * 512;
    unsigned short* lB2 = sB + 2048 + wave * 512;

    f32x4 acc[4][4];
    #pragma unroll
    for (int i = 0; i < 4; ++i)
        #pragma unroll
        for (int j = 0; j < 4; ++j)
            #pragma unroll
            for (int q = 0; q < 4; ++q) acc[i][j][q] = 0.0f;

    const int ao = (wm * 64 + r16) * 32 + lg * 8;
    const int bo = (wn * 64 + r16) * 32 + lg * 8;

    #pragma unroll 1
    for (int kt = 0; kt < ksl; kt += 32) {
        GLOAD_LDS16(gA, lA1); GLOAD_LDS16(gA2, lA2);
        GLOAD_LDS16(gB, lB1); GLOAD_LDS16(gB2, lB2);
        gA += 32; gA2 += 32; gB += 32; gB2 += 32;
        __syncthreads();
        bf16x8 af[4], bfr[4];
        #pragma unroll
        for (int i = 0; i < 4; ++i) af[i]  = *(const bf16x8*)(sA + ao + i * 512);
        #pragma unroll
        for (int j = 0; j < 4; ++j) bfr[j] = *(const bf16x8*)(sB + bo + j * 512);
        #pragma unroll
        for (int i = 0; i < 4; ++i)
            #pragma unroll
            for (int j = 0; j < 4; ++j)
                acc[i][j] = __builtin_amdgcn_mfma_f32_16x16x32_bf16(af[i], bfr[j], acc[i][j], 0, 0, 0);
        __syncthreads();
    }
    float* Cz = Cpart + (size_t)z * (size_t)M * N;
    #pragma unroll
    for (int i = 0; i < 4; ++i)
        #pragma unroll
        for (int j = 0; j < 4; ++j)
            #pragma unroll
            for (int q = 0; q < 4; ++q) {
                int row = row0 + wm * 64 + i * 16 + lg * 4 + q;
                int col = col0 + wn * 64 + j * 16 + r16;
                Cz[(size_t)row * N + col] = acc[i][j][q];
            }
}

// ---------------- 256^2 u-GEMM, 2x32-MFMA phases, spread staging, fused energy epilogue ------
// A = es_bf16 (16384 x 2048); B = U_w_bf16 (1024 x 2048). grid (4, 64), 512 threads.
// LDS: 2 tile-bufs x 64KB ([A(2x128x64)][B(2x128x64)]), T2 XOR-swizzle (pre-swizzled source).
__global__ __launch_bounds__(512, 2) void gemm_energy256(
        const unsigned short* __restrict__ A, const unsigned short* __restrict__ B,
        const float* __restrict__ attn_w, const float* __restrict__ U_b,
        const float* __restrict__ wbuf, float* __restrict__ e_part) {
    const int NT = 32;                                     // 2048 / 64
    __shared__ __align__(16) unsigned short lds[65536];    // 128 KiB

    const int t = threadIdx.x;
    const int w = t >> 6, lane = t & 63;
    const int wm = w >> 2, wn = w & 3;
    const int lg = lane >> 4, r16 = lane & 15;

    int d = blockIdx.y * gridDim.x + blockIdx.x;
    int f = (d & 7) * 32 + (d >> 3);                       // bijective (256 % 8 == 0)
    const int bx = f & 3, by = f >> 2;
    const int row0 = by * 256, col0 = bx * 256;

    // chunk c = q*8 + w: mat=c>>5, half=(c>>4)&1, rowgrp=c&15; lane: row rg*8+(l>>3),
    // global 16B-slot pre-swizzled: (l&7)^(l>>3)  [same involution applied on read]
    const unsigned short* gbase[8];
    unsigned lbase[8];
    #pragma unroll
    for (int q = 0; q < 8; ++q) {
        int c = q * 8 + w;
        int mat = c >> 5, half = (c >> 4) & 1, rg = c & 15;
        int rih = rg * 8 + (lane >> 3);
        int slot = (lane & 7) ^ (lane >> 3);
        gbase[q] = (mat == 0)
            ? A + (size_t)(row0 + half * 128 + rih) * 2048 + slot * 8
            : B + (size_t)(col0 + half * 128 + rih) * 2048 + slot * 8;
        lbase[q] = (unsigned)(mat * 32768 + half * 16384 + rg * 1024);
    }

#define STAGE_R(T, cbuf, QLO, QHI) do { \
    char* lp_ = (char*)lds + (cbuf) * 65536; \
    _Pragma("unroll") \
    for (int q_ = (QLO); q_ < (QHI); ++q_) \
        GLOAD_LDS16(gbase[q_] + (size_t)(T) * 64, lp_ + lbase[q_]); \
} while (0)

    const unsigned swz = (unsigned)((lg ^ (r16 & 7)) * 16);
    const unsigned aoff0 = (unsigned)(wm * 16384 + r16 * 128) + swz;
    const unsigned boff0 = (unsigned)(32768 + (wn >> 1) * 16384 + ((wn & 1) * 64 + r16) * 128) + swz;

    f32x4 acc[8][4];
    #pragma unroll
    for (int m = 0; m < 8; ++m)
        #pragma unroll
        for (int n = 0; n < 4; ++n)
            #pragma unroll
            for (int q = 0; q < 4; ++q) acc[m][n][q] = 0.0f;

// one phase: 12 ds_read_b128 + 32 MFMA (compiler interleaves with fine lgkmcnt)
#define KK(LP, KKB) do { \
    bf16x8 bfr_[4], af_[8]; \
    _Pragma("unroll") \
    for (int n_ = 0; n_ < 4; ++n_) \
        bfr_[n_] = *(const bf16x8*)((LP) + ((boff0 + n_ * 2048) ^ (KKB))); \
    _Pragma("unroll") \
    for (int m_ = 0; m_ < 8; ++m_) \
        af_[m_] = *(const bf16x8*)((LP) + ((aoff0 + m_ * 2048) ^ (KKB))); \
    __builtin_amdgcn_s_setprio(1); \
    _Pragma("unroll") \
    for (int m_ = 0; m_ < 8; ++m_) \
        _Pragma("unroll") \
        for (int n_ = 0; n_ < 4; ++n_) \
            acc[m_][n_] = __builtin_amdgcn_mfma_f32_16x16x32_bf16( \
                af_[m_], bfr_[n_], acc[m_][n_], 0, 0, 0); \
    __builtin_amdgcn_s_setprio(0); \
} while (0)

    STAGE_R(0, 0, 0, 8);
    #pragma unroll 1
    for (int tt = 0; tt < NT - 1; ++tt) {
        const char* lp = (const char*)lds + (tt & 1) * 65536;
        STAGE_R(tt + 1, (tt + 1) & 1, 0, 4);   // A halves of next tile
        WAITV(4);                              // tile tt's 8 loads (oldest) landed
        BARR;                                  // publish tile tt
        KK(lp, 0);
        STAGE_R(tt + 1, (tt + 1) & 1, 4, 8);   // B halves of next tile
        BARR;
        KK(lp, 64);
        BARR;                                  // fences buf reads before next overwrite
    }
    {
        const char* lp = (const char*)lds + ((NT - 1) & 1) * 65536;
        WAITV(0);
        BARR;
        KK(lp, 0);
        BARR;
        KK(lp, 64);
    }
#undef STAGE_R
#undef KK

    // fused energy epilogue
    float aw[4], ub[4];
    #pragma unroll
    for (int n = 0; n < 4; ++n) {
        int col = col0 + wn * 64 + n * 16 + r16;
        aw[n] = attn_w[col];
        ub[n] = U_b[col];
    }
    #pragma unroll
    for (int m = 0; m < 8; ++m)
        #pragma unroll
        for (int q = 0; q < 4; ++q) {
            int lrow = wm * 128 + m * 16 + lg * 4 + q;     // local row = batch index
            const float* wrow = wbuf + (size_t)lrow * 1024;
            float e = 0.f;
            #pragma unroll
            for (int n = 0; n < 4; ++n) {
                int col = col0 + wn * 64 + n * 16 + r16;
                float cc = acc[m][n][q] + ub[n] + wrow[col];
                float ex = __expf(2.f * cc);               // tanh via exp
                e += aw[n] * (1.f - 2.f / (ex + 1.f));
            }
            e += __shfl_xor(e, 1); e += __shfl_xor(e, 2);
            e += __shfl_xor(e, 4); e += __shfl_xor(e, 8);
            if (r16 == 0) e_part[(size_t)(row0 + lrow) * 16 + bx * 4 + wn] = e;
        }
}

// softmax over s (64 lanes) per n
__global__ __launch_bounds__(256) void k_softmax2(const float* __restrict__ e_part,
                                                  float* __restrict__ attn) {
    int w = threadIdx.x >> 6, s = threadIdx.x & 63;
    int n = blockIdx.x * 4 + w;
    const float* p = e_part + ((size_t)(s * 256 + n)) * 16;
    float v = 0.f;
    #pragma unroll
    for (int k = 0; k < 16; ++k) v += p[k];
    float mx = v;
    #pragma unroll
    for (int o = 1; o < 64; o <<= 1) mx = fmaxf(mx, __shfl_xor(mx, o));
    float e = __expf(v - mx);
    float sum = e;
    #pragma unroll
    for (int o = 1; o < 64; o <<= 1) sum += __shfl_xor(sum, o);
    attn[s * 256 + n] = e / sum;
}

// context + emb gather -> A0
__global__ void k_context(const unsigned short* __restrict__ esb, const float* __restrict__ attn,
                          const float* __restrict__ emb, const int* __restrict__ x,
                          unsigned short* __restrict__ A0) {
    int n = blockIdx.x, t = threadIdx.x;
    __shared__ float as_[64];
    if (t < 64) as_[t] = attn[t * 256 + n];
    __syncthreads();
    float acc[8];
    #pragma unroll
    for (int k = 0; k < 8; ++k) acc[k] = 0.f;
    const unsigned short* base = esb + (size_t)n * 2048 + t * 8;
    for (int s = 0; s < 64; ++s) {
        bf16x8 v = *(const bf16x8*)(base + (size_t)s * 524288);
        float a = as_[s];
        #pragma unroll
        for (int k = 0; k < 8; ++k) acc[k] += a * bf2f((unsigned short)v[k]);
    }
    bf16x8 o;
    #pragma unroll
    for (int k = 0; k < 8; ++k) o[k] = (short)f2bf(acc[k]);
    *(bf16x8*)(A0 + (size_t)n * 3328 + t * 8) = o;
    if (t < 32) {
        const float4* e4 = (const float4*)(emb + (size_t)x[n] * 256 + t * 8);
        *(bf16x8*)(A0 + (size_t)n * 3328 + 2048 + t * 8) = pack8(e4[0], e4[1]);
    }
}

// GRU gate math; sums 4 split-K partials of g: [Z][256][4096] = [r | z | i_n | h_n]
__global__ void k_gru(const float* __restrict__ g, const float* __restrict__ b_ih,
                      const float* __restrict__ b_hh, const float* __restrict__ h_in,
                      float* __restrict__ h_out, unsigned short* __restrict__ a_dst,
                      int dst_pitch) {
    int i = blockIdx.x * blockDim.x + threadIdx.x;   // 262144
    int n = i >> 10, e = i & 1023;
    const float* gn = g + (size_t)n * 4096;
    float rr = 0.f, zz = 0.f, in_ = 0.f, hn_ = 0.f;
    #pragma unroll
    for (int z = 0; z < 4; ++z) {
        const float* gz = gn + (size_t)z * 1048576;
        rr  += gz[e];
        zz  += gz[1024 + e];
        in_ += gz[2048 + e];
        hn_ += gz[3072 + e];
    }
    rr  += b_ih[e]        + b_hh[e];
    zz  += b_ih[1024 + e] + b_hh[1024 + e];
    in_ += b_ih[2048 + e];
    hn_ += b_hh[2048 + e];
    float r = 1.f / (1.f + __expf(-rr));
    float z = 1.f / (1.f + __expf(-zz));
    float ex = __expf(2.f * (in_ + r * hn_));
    float nn = 1.f - 2.f / (ex + 1.f);
    float h = h_in[i];
    float ho = (1.f - z) * nn + z * h;
    h_out[i] = ho;
    a_dst[(size_t)n * dst_pitch + e] = f2bf(ho);
}

// sum 4 split-K partials + bias (w matrix: 256x1024)
__global__ void k_wsum(const float* __restrict__ Wp, const float* __restrict__ W_b,
                       float* __restrict__ Wout) {
    int i = blockIdx.x * blockDim.x + threadIdx.x;   // 262144
    Wout[i] = Wp[i] + Wp[262144 + i] + Wp[524288 + i] + Wp[786432 + i] + W_b[i & 1023];
}

// sum 4 split-K partials + bias (predictions: 256x128)
__global__ void k_fcsum(const float* __restrict__ Fp, const float* __restrict__ fc_b,
                        float* __restrict__ outp) {
    int i = blockIdx.x * blockDim.x + threadIdx.x;   // 32768
    outp[i] = Fp[i] + Fp[32768 + i] + Fp[65536 + i] + Fp[98304 + i] + fc_b[i & 127];
}

// ---------------- launch ----------------

extern "C" void kernel_launch(void* const* d_in, const int* in_sizes, int n_in,
                              void* d_out, int out_size, void* d_ws, size_t ws_size,
                              hipStream_t stream) {
    const int*   x      = (const int*)  d_in[0];
    const float* es     = (const float*)d_in[1];
    const float* hidden = (const float*)d_in[2];
    const float* emb    = (const float*)d_in[4];
    const float* U_w    = (const float*)d_in[5];
    const float* U_b    = (const float*)d_in[6];
    const float* W_w    = (const float*)d_in[7];
    const float* W_b    = (const float*)d_in[8];
    const float* attn_w = (const float*)d_in[9];
    const float* W_ih0  = (const float*)d_in[11];
    const float* W_hh0  = (const float*)d_in[12];
    const float* b_ih0  = (const float*)d_in[13];
    const float* b_hh0  = (const float*)d_in[14];
    const float* W_ih1  = (const float*)d_in[15];
    const float* W_hh1  = (const float*)d_in[16];
    const float* b_ih1  = (const float*)d_in[17];
    const float* b_hh1  = (const float*)d_in[18];
    const float* fc_w   = (const float*)d_in[19];
    const float* fc_b   = (const float*)d_in[20];

    float* out        = (float*)d_out;
    float* out_pred   = out;
    float* out_hidden = out + 32768;
    float* out_attn   = out + 32768 + 524288;

    char* ws = (char*)d_ws;
    size_t off = 0;
    auto alloc = [&](size_t bytes) { char* p = ws + off; off += (bytes + 255) & ~(size_t)255; return p; };
    unsigned short* ES_BF  = (unsigned short*)alloc((size_t)16384 * 2048 * 2);
    unsigned short* UW_BF  = (unsigned short*)alloc((size_t)1024 * 2048 * 2);
    unsigned short* WW_BF  = (unsigned short*)alloc((size_t)1024 * 1024 * 2);
    unsigned short* FCW_BF = (unsigned short*)alloc((size_t)128 * 1024 * 2);
    unsigned short* H1_BF  = (unsigned short*)alloc((size_t)256 * 1024 * 2);
    unsigned short* B0     = (unsigned short*)alloc((size_t)4096 * 3328 * 2);
    unsigned short* B1     = (unsigned short*)alloc((size_t)4096 * 2048 * 2);
    unsigned short* A0     = (unsigned short*)alloc((size_t)256 * 3328 * 2);
    unsigned short* A1     = (unsigned short*)alloc((size_t)256 * 2048 * 2);
    unsigned short* FCA    = (unsigned short*)alloc((size_t)256 * 1024 * 2);
    float* WBUF  = (float*)alloc((size_t)256 * 1024 * 4);
    float* EPART = (float*)alloc((size_t)16384 * 16 * 4);
    float* WP    = (float*)alloc((size_t)4 * 256 * 1024 * 4);   // w partials; reused for fc partials
    float* G0P   = (float*)alloc((size_t)4 * 256 * 4096 * 4);   // GRU0 partials; reused for GRU1
    float* FCP   = WP;
    float* G1P   = G0P;

    // fused prep (7,389,184 chunks of 8 elems)
    k_prep<<<28864, 256, 0, stream>>>(es, U_w, W_w, fc_w, hidden, W_ih0, W_hh0, W_ih1, W_hh1,
                                      ES_BF, UW_BF, WW_BF, FCW_BF, A0, A1, H1_BF, B0, B1);
    // w = hidden[1] @ W_w^T + W_b  (split-K 4)
    gemm_bt_sk<<<dim3(8, 2, 4), 256, 0, stream>>>(H1_BF, WW_BF, WP, 1024, 1024, 256);
    k_wsum<<<1024, 256, 0, stream>>>(WP, W_b, WBUF);
    // u-GEMM + fused energy epilogue
    gemm_energy256<<<dim3(4, 64), 512, 0, stream>>>(ES_BF, UW_BF, attn_w, U_b, WBUF, EPART);
    // attention softmax
    k_softmax2<<<64, 256, 0, stream>>>(EPART, out_attn);
    // context + embedding -> A0
    k_context<<<256, 256, 0, stream>>>(ES_BF, out_attn, emb, x, A0);
    // GRU layer 0 (split-K 4: 3328 = 4*832)
    gemm_bt_sk<<<dim3(32, 2, 4), 256, 0, stream>>>(A0, B0, G0P, 4096, 3328, 832);
    k_gru<<<1024, 256, 0, stream>>>(G0P, b_ih0, b_hh0, hidden, out_hidden, A1, 2048);
    // GRU layer 1 (split-K 4: 2048 = 4*512)
    gemm_bt_sk<<<dim3(32, 2, 4), 256, 0, stream>>>(A1, B1, G1P, 4096, 2048, 512);
    k_gru<<<1024, 256, 0, stream>>>(G1P, b_ih1, b_hh1, hidden + 262144, out_hidden + 262144, FCA, 1024);
    // predictions = h1 @ fc_w^T + fc_b (split-K 4)
    gemm_bt_sk<<<dim3(1, 2, 4), 256, 0, stream>>>(FCA, FCW_BF, FCP, 128, 1024, 256);
    k_fcsum<<<128, 256, 0, stream>>>(FCP, fc_b, out_pred);
}

// Round 4
// 211.769 us; speedup vs baseline: 1.9613x; 1.0053x over previous
//
#include <hip/hip_runtime.h>
#include <stdint.h>

typedef __attribute__((ext_vector_type(8))) short bf16x8;   // 8 bf16 = 4 VGPRs
typedef __attribute__((ext_vector_type(4))) float f32x4;

#define DEVI __device__ __forceinline__

DEVI unsigned short f2bf(float f) {
    union { float f; uint32_t u; } v; v.f = f;
    uint32_t r = v.u + 0x7FFFu + ((v.u >> 16) & 1u);   // RNE
    return (unsigned short)(r >> 16);
}
DEVI float bf2f(unsigned short h) {
    union { uint32_t u; float f; } v; v.u = ((uint32_t)h) << 16;
    return v.f;
}
DEVI bf16x8 pack8(float4 a, float4 b) {
    bf16x8 o;
    o[0]=(short)f2bf(a.x); o[1]=(short)f2bf(a.y); o[2]=(short)f2bf(a.z); o[3]=(short)f2bf(a.w);
    o[4]=(short)f2bf(b.x); o[5]=(short)f2bf(b.y); o[6]=(short)f2bf(b.z); o[7]=(short)f2bf(b.w);
    return o;
}

#define GLOAD_LDS16(gsrc, ldst) \
    __builtin_amdgcn_global_load_lds((__attribute__((address_space(1))) void*)(gsrc), \
                                     (__attribute__((address_space(3))) void*)(ldst), 16, 0, 0)

#define BARR asm volatile("s_barrier" ::: "memory")
#define WAITV(n) asm volatile("s_waitcnt vmcnt(" #n ")" ::: "memory")
#define LGKM0 do { asm volatile("s_waitcnt lgkmcnt(0)" ::: "memory"); \
                   __builtin_amdgcn_sched_barrier(0); } while (0)

// ---------------- fused prep: all fp32->bf16 conversions + GRU weight assembly ----------------
__global__ void k_prep(const float* __restrict__ es, const float* __restrict__ U_w,
                       const float* __restrict__ W_w, const float* __restrict__ fc_w,
                       const float* __restrict__ hidden,
                       const float* __restrict__ Wih0, const float* __restrict__ Whh0,
                       const float* __restrict__ Wih1, const float* __restrict__ Whh1,
                       unsigned short* __restrict__ ES_BF, unsigned short* __restrict__ UW_BF,
                       unsigned short* __restrict__ WW_BF, unsigned short* __restrict__ FCW_BF,
                       unsigned short* __restrict__ A0, unsigned short* __restrict__ A1,
                       unsigned short* __restrict__ H1B,
                       unsigned short* __restrict__ B0, unsigned short* __restrict__ B1) {
    int i = blockIdx.x * blockDim.x + threadIdx.x;
    const int S0 = 4194304, S1 = S0 + 262144, S2 = S1 + 131072, S3 = S2 + 16384;
    const int S4 = S3 + 32768, S5 = S4 + 1703936, S6 = S5 + 1048576;
    if (i < S0) {
        const float4* s = (const float4*)(es + (size_t)i * 8);
        *(bf16x8*)(ES_BF + (size_t)i * 8) = pack8(s[0], s[1]);
    } else if (i < S1) {
        int j = i - S0;
        const float4* s = (const float4*)(U_w + (size_t)j * 8);
        *(bf16x8*)(UW_BF + (size_t)j * 8) = pack8(s[0], s[1]);
    } else if (i < S2) {
        int j = i - S1;
        const float4* s = (const float4*)(W_w + (size_t)j * 8);
        *(bf16x8*)(WW_BF + (size_t)j * 8) = pack8(s[0], s[1]);
    } else if (i < S3) {
        int j = i - S2;
        const float4* s = (const float4*)(fc_w + (size_t)j * 8);
        *(bf16x8*)(FCW_BF + (size_t)j * 8) = pack8(s[0], s[1]);
    } else if (i < S4) {
        int j = i - S3;
        int n = j >> 7, e0 = (j & 127) * 8;
        const float4* p0 = (const float4*)(hidden + (size_t)n * 1024 + e0);
        const float4* p1 = (const float4*)(hidden + 262144 + (size_t)n * 1024 + e0);
        bf16x8 o0 = pack8(p0[0], p0[1]);
        bf16x8 o1 = pack8(p1[0], p1[1]);
        *(bf16x8*)(A0 + (size_t)n * 3328 + 2304 + e0) = o0;
        *(bf16x8*)(A1 + (size_t)n * 2048 + 1024 + e0) = o1;
        *(bf16x8*)(H1B + (size_t)n * 1024 + e0) = o1;
    } else if (i < S5) {
        unsigned j = (unsigned)(i - S4);
        unsigned r = j / 416u;
        int kc = (int)(j - r * 416u) * 8;
        const float* src = nullptr;
        if (r < 2048)      src = (kc < 2304) ? (Wih0 + (size_t)r * 2304 + kc)
                                             : (Whh0 + (size_t)r * 1024 + (kc - 2304));
        else if (r < 3072) { if (kc < 2304)  src = Wih0 + (size_t)r * 2304 + kc; }
        else               { if (kc >= 2304) src = Whh0 + (size_t)(r - 1024) * 1024 + (kc - 2304); }
        bf16x8 o;
        if (src) { const float4* s4 = (const float4*)src; o = pack8(s4[0], s4[1]); }
        else     { for (int k = 0; k < 8; ++k) o[k] = 0; }
        *(bf16x8*)(B0 + (size_t)r * 3328 + kc) = o;
    } else if (i < S6) {
        int j = i - S5;
        int r = j >> 8;
        int kc = (j & 255) * 8;
        const float* src = nullptr;
        if (r < 2048)      src = (kc < 1024) ? (Wih1 + (size_t)r * 1024 + kc)
                                             : (Whh1 + (size_t)r * 1024 + (kc - 1024));
        else if (r < 3072) { if (kc < 1024)  src = Wih1 + (size_t)r * 1024 + kc; }
        else               { if (kc >= 1024) src = Whh1 + (size_t)(r - 1024) * 1024 + (kc - 1024); }
        bf16x8 o;
        if (src) { const float4* s4 = (const float4*)src; o = pack8(s4[0], s4[1]); }
        else     { for (int k = 0; k < 8; ++k) o[k] = 0; }
        *(bf16x8*)(B1 + (size_t)r * 2048 + kc) = o;
    }
}

// ---------------- split-K GEMM: Cpart[z] = A(MxK[slice z]) * B(NxK)^T ----------------
__global__ __launch_bounds__(256) void gemm_bt_sk(
        const unsigned short* __restrict__ A, const unsigned short* __restrict__ B,
        float* __restrict__ Cpart, int N, int K, int ksl) {
    __shared__ unsigned short sA[4096];
    __shared__ unsigned short sB[4096];
    const int nbx = gridDim.x;
    const int nwg = nbx * gridDim.y;
    int d = blockIdx.y * nbx + blockIdx.x;
    int f = d;
    if ((nwg & 7) == 0) { int cpx = nwg >> 3; f = (d & 7) * cpx + (d >> 3); }
    const int bx = f % nbx, by = f / nbx;
    const int z = blockIdx.z;
    const int t = threadIdx.x, wave = t >> 6, lane = t & 63;
    const int wm = wave >> 1, wn = wave & 1;
    const int lg = lane >> 4, r16 = lane & 15;
    const int row0 = by * 128, col0 = bx * 128;
    const int M = gridDim.y * 128;

    const int cr = t >> 2, ckc = (t & 3) * 8;
    const unsigned short* gA  = A + (size_t)(row0 + cr) * K + (size_t)z * ksl + ckc;
    const unsigned short* gA2 = gA + (size_t)64 * K;
    const unsigned short* gB  = B + (size_t)(col0 + cr) * K + (size_t)z * ksl + ckc;
    const unsigned short* gB2 = gB + (size_t)64 * K;
    unsigned short* lA1 = sA + wave * 512;
    unsigned short* lA2 = sA + 2048 + wave * 512;
    unsigned short* lB1 = sB + wave * 512;
    unsigned short* lB2 = sB + 2048 + wave * 512;

    f32x4 acc[4][4];
    #pragma unroll
    for (int i = 0; i < 4; ++i)
        #pragma unroll
        for (int j = 0; j < 4; ++j)
            #pragma unroll
            for (int q = 0; q < 4; ++q) acc[i][j][q] = 0.0f;

    const int ao = (wm * 64 + r16) * 32 + lg * 8;
    const int bo = (wn * 64 + r16) * 32 + lg * 8;

    #pragma unroll 1
    for (int kt = 0; kt < ksl; kt += 32) {
        GLOAD_LDS16(gA, lA1); GLOAD_LDS16(gA2, lA2);
        GLOAD_LDS16(gB, lB1); GLOAD_LDS16(gB2, lB2);
        gA += 32; gA2 += 32; gB += 32; gB2 += 32;
        __syncthreads();
        bf16x8 af[4], bfr[4];
        #pragma unroll
        for (int i = 0; i < 4; ++i) af[i]  = *(const bf16x8*)(sA + ao + i * 512);
        #pragma unroll
        for (int j = 0; j < 4; ++j) bfr[j] = *(const bf16x8*)(sB + bo + j * 512);
        #pragma unroll
        for (int i = 0; i < 4; ++i)
            #pragma unroll
            for (int j = 0; j < 4; ++j)
                acc[i][j] = __builtin_amdgcn_mfma_f32_16x16x32_bf16(af[i], bfr[j], acc[i][j], 0, 0, 0);
        __syncthreads();
    }
    float* Cz = Cpart + (size_t)z * (size_t)M * N;
    #pragma unroll
    for (int i = 0; i < 4; ++i)
        #pragma unroll
        for (int j = 0; j < 4; ++j)
            #pragma unroll
            for (int q = 0; q < 4; ++q) {
                int row = row0 + wm * 64 + i * 16 + lg * 4 + q;
                int col = col0 + wn * 64 + j * 16 + r16;
                Cz[(size_t)row * N + col] = acc[i][j][q];
            }
}

// ---------------- 256^2 u-GEMM, faithful m201 8-phase/iter schedule ----------------
// A = es_bf16 (16384 x 2048); B = U_w_bf16 (1024 x 2048). grid (4, 64), 512 threads, 8 waves.
// Per K-tile (BK=64): 4 phases x {dsr 4-8, stage 0-4 gload, barrier, lgkm0+sb0, prio1,
// 16 MFMA (one C-quadrant), prio0, barrier}. A-halves staged ph0 (HBM/L3 latency, 3-phase
// cover), B-halves ph1 (L2-hot, 2-phase cover); vmcnt drain at ph3 is covered, not exposed.
__global__ __launch_bounds__(512, 2) void gemm_energy256(
        const unsigned short* __restrict__ A, const unsigned short* __restrict__ B,
        const float* __restrict__ attn_w, const float* __restrict__ U_b,
        const float* __restrict__ wbuf, float* __restrict__ e_part) {
    const int NT = 32;                                     // 2048 / 64
    __shared__ __align__(16) unsigned short lds[65536];    // 2 slots x 64 KiB

    const int t = threadIdx.x;
    const int w = t >> 6, lane = t & 63;
    const int wm = w >> 2, wn = w & 3;
    const int lg = lane >> 4, r16 = lane & 15;

    int d = blockIdx.y * gridDim.x + blockIdx.x;
    int f = (d & 7) * 32 + (d >> 3);                       // bijective (256 % 8 == 0)
    const int bx = f & 3, by = f >> 2;
    const int row0 = by * 256, col0 = bx * 256;

    // chunk c = q*8 + w: mat=c>>5 (q<4 -> A, q>=4 -> B), half=(c>>4)&1, rowgrp=c&15
    // lane l: row rg*8+(l>>3); global 16B-slot pre-swizzled (l&7)^(l>>3) [involution on read]
    const unsigned short* gbase[8];
    unsigned lbase[8];
    #pragma unroll
    for (int q = 0; q < 8; ++q) {
        int c = q * 8 + w;
        int mat = c >> 5, half = (c >> 4) & 1, rg = c & 15;
        int rih = rg * 8 + (lane >> 3);
        int slot = (lane & 7) ^ (lane >> 3);
        gbase[q] = (mat == 0)
            ? A + (size_t)(row0 + half * 128 + rih) * 2048 + slot * 8
            : B + (size_t)(col0 + half * 128 + rih) * 2048 + slot * 8;
        lbase[q] = (unsigned)(mat * 32768 + half * 16384 + rg * 1024);
    }

#define STAGE4(T, cbuf, QLO) do { \
    char* lp_ = (char*)lds + (cbuf) * 65536; \
    _Pragma("unroll") \
    for (int q_ = (QLO); q_ < (QLO) + 4; ++q_) \
        GLOAD_LDS16(gbase[q_] + (size_t)(T) * 64, lp_ + lbase[q_]); \
} while (0)

    const unsigned swz = (unsigned)((lg ^ (r16 & 7)) * 16);
    const unsigned aoff0 = (unsigned)(wm * 16384 + r16 * 128) + swz;
    const unsigned boff0 = (unsigned)(32768 + (wn >> 1) * 16384 + ((wn & 1) * 64 + r16) * 128) + swz;

    f32x4 acc[8][4];
    #pragma unroll
    for (int m = 0; m < 8; ++m)
        #pragma unroll
        for (int n = 0; n < 4; ++n)
            #pragma unroll
            for (int q = 0; q < 4; ++q) acc[m][n][q] = 0.0f;

    bf16x8 bfr[4], afr[4];

#define DSB(LP, KK) do { \
    _Pragma("unroll") \
    for (int n_ = 0; n_ < 4; ++n_) \
        bfr[n_] = *(const bf16x8*)((LP) + ((boff0 + n_ * 2048) ^ ((KK) << 6))); \
} while (0)

#define DSA(LP, MH, KK) do { \
    _Pragma("unroll") \
    for (int m_ = 0; m_ < 4; ++m_) \
        afr[m_] = *(const bf16x8*)((LP) + ((aoff0 + ((MH) * 4 + m_) * 2048) ^ ((KK) << 6))); \
} while (0)

#define MM(MH) do { \
    __builtin_amdgcn_s_setprio(1); \
    _Pragma("unroll") \
    for (int m_ = 0; m_ < 4; ++m_) \
        _Pragma("unroll") \
        for (int n_ = 0; n_ < 4; ++n_) \
            acc[(MH) * 4 + m_][n_] = __builtin_amdgcn_mfma_f32_16x16x32_bf16( \
                afr[m_], bfr[n_], acc[(MH) * 4 + m_][n_], 0, 0, 0); \
    __builtin_amdgcn_s_setprio(0); \
} while (0)

    // prologue: stage tile 0 into slot 0
    STAGE4(0, 0, 0); STAGE4(0, 0, 4);
    WAITV(0);
    BARR;

    #pragma unroll 1
    for (int tt = 0; tt < NT; ++tt) {
        const char* lp = (const char*)lds + (tt & 1) * 65536;
        const int nbuf = (tt & 1) ^ 1;
        const bool more = (tt + 1 < NT);
        // ph0: B(kk0) + A(mh0,kk0); stage next-tile A-halves
        DSB(lp, 0); DSA(lp, 0, 0);
        if (more) STAGE4(tt + 1, nbuf, 0);
        BARR; LGKM0; MM(0);
        BARR;
        // ph1: A(mh1,kk0); stage next-tile B-halves
        DSA(lp, 1, 0);
        if (more) STAGE4(tt + 1, nbuf, 4);
        BARR; LGKM0; MM(1);
        BARR;
        // ph2: B(kk1) + A(mh0,kk1)
        DSB(lp, 1); DSA(lp, 0, 1);
        BARR; LGKM0; MM(0);
        BARR;
        // ph3: A(mh1,kk1); wait next tile's loads (2-3 phases of cover) + publish
        DSA(lp, 1, 1);
        WAITV(0);
        BARR; LGKM0; MM(1);
        BARR;
    }
#undef STAGE4
#undef DSB
#undef DSA
#undef MM

    // fused energy epilogue: e_part[row*16 + bx*4 + wn]
    float aw[4], ub[4];
    #pragma unroll
    for (int n = 0; n < 4; ++n) {
        int col = col0 + wn * 64 + n * 16 + r16;
        aw[n] = attn_w[col];
        ub[n] = U_b[col];
    }
    #pragma unroll
    for (int m = 0; m < 8; ++m)
        #pragma unroll
        for (int q = 0; q < 4; ++q) {
            int lrow = wm * 128 + m * 16 + lg * 4 + q;     // local row = batch index
            const float* wrow = wbuf + (size_t)lrow * 1024;
            float e = 0.f;
            #pragma unroll
            for (int n = 0; n < 4; ++n) {
                int col = col0 + wn * 64 + n * 16 + r16;
                float cc = acc[m][n][q] + ub[n] + wrow[col];
                float ex = __expf(2.f * cc);               // tanh via exp
                e += aw[n] * (1.f - 2.f / (ex + 1.f));
            }
            e += __shfl_xor(e, 1); e += __shfl_xor(e, 2);
            e += __shfl_xor(e, 4); e += __shfl_xor(e, 8);
            if (r16 == 0) e_part[(size_t)(row0 + lrow) * 16 + bx * 4 + wn] = e;
        }
}

// ---------------- fused softmax + context + emb gather ----------------
// block n (256 blocks, 256 threads): softmax over s=64 from e_part, write attn,
// then context[n,:] = sum_s attn[s,n]*es[s,n,:] -> A0[:,0:2048]; emb -> A0[:,2048:2304]
__global__ __launch_bounds__(256) void k_softctx(
        const unsigned short* __restrict__ esb, const float* __restrict__ e_part,
        const float* __restrict__ emb, const int* __restrict__ x,
        float* __restrict__ attn_out, unsigned short* __restrict__ A0) {
    int n = blockIdx.x, t = threadIdx.x;
    __shared__ float as_[64];
    {   // energy reduce: thread t -> s = t>>2, quarter (t&3)
        int s = t >> 2;
        const float* p = e_part + ((size_t)(s * 256 + n)) * 16 + (t & 3) * 4;
        float v = p[0] + p[1] + p[2] + p[3];
        v += __shfl_xor(v, 1); v += __shfl_xor(v, 2);
        __shared__ float ev[64];
        if ((t & 3) == 0) ev[s] = v;
        __syncthreads();
        if (t < 64) {                       // wave 0: softmax over 64 s-values
            float e = ev[t];
            float mx = e;
            #pragma unroll
            for (int o = 1; o < 64; o <<= 1) mx = fmaxf(mx, __shfl_xor(mx, o));
            float ee = __expf(e - mx);
            float sum = ee;
            #pragma unroll
            for (int o = 1; o < 64; o <<= 1) sum += __shfl_xor(sum, o);
            float a = ee / sum;
            as_[t] = a;
            attn_out[t * 256 + n] = a;
        }
        __syncthreads();
    }
    float acc[8];
    #pragma unroll
    for (int k = 0; k < 8; ++k) acc[k] = 0.f;
    const unsigned short* base = esb + (size_t)n * 2048 + t * 8;
    for (int s = 0; s < 64; ++s) {
        bf16x8 v = *(const bf16x8*)(base + (size_t)s * 524288);
        float a = as_[s];
        #pragma unroll
        for (int k = 0; k < 8; ++k) acc[k] += a * bf2f((unsigned short)v[k]);
    }
    bf16x8 o;
    #pragma unroll
    for (int k = 0; k < 8; ++k) o[k] = (short)f2bf(acc[k]);
    *(bf16x8*)(A0 + (size_t)n * 3328 + t * 8) = o;
    if (t < 32) {
        const float4* e4 = (const float4*)(emb + (size_t)x[n] * 256 + t * 8);
        *(bf16x8*)(A0 + (size_t)n * 3328 + 2048 + t * 8) = pack8(e4[0], e4[1]);
    }
}

// GRU gate math; sums 4 split-K partials of g: [Z][256][4096] = [r | z | i_n | h_n]
__global__ void k_gru(const float* __restrict__ g, const float* __restrict__ b_ih,
                      const float* __restrict__ b_hh, const float* __restrict__ h_in,
                      float* __restrict__ h_out, unsigned short* __restrict__ a_dst,
                      int dst_pitch) {
    int i = blockIdx.x * blockDim.x + threadIdx.x;   // 262144
    int n = i >> 10, e = i & 1023;
    const float* gn = g + (size_t)n * 4096;
    float rr = 0.f, zz = 0.f, in_ = 0.f, hn_ = 0.f;
    #pragma unroll
    for (int z = 0; z < 4; ++z) {
        const float* gz = gn + (size_t)z * 1048576;
        rr  += gz[e];
        zz  += gz[1024 + e];
        in_ += gz[2048 + e];
        hn_ += gz[3072 + e];
    }
    rr  += b_ih[e]        + b_hh[e];
    zz  += b_ih[1024 + e] + b_hh[1024 + e];
    in_ += b_ih[2048 + e];
    hn_ += b_hh[2048 + e];
    float r = 1.f / (1.f + __expf(-rr));
    float z = 1.f / (1.f + __expf(-zz));
    float ex = __expf(2.f * (in_ + r * hn_));
    float nn = 1.f - 2.f / (ex + 1.f);
    float h = h_in[i];
    float ho = (1.f - z) * nn + z * h;
    h_out[i] = ho;
    a_dst[(size_t)n * dst_pitch + e] = f2bf(ho);
}

// sum 4 split-K partials + bias (w matrix: 256x1024)
__global__ void k_wsum(const float* __restrict__ Wp, const float* __restrict__ W_b,
                       float* __restrict__ Wout) {
    int i = blockIdx.x * blockDim.x + threadIdx.x;   // 262144
    Wout[i] = Wp[i] + Wp[262144 + i] + Wp[524288 + i] + Wp[786432 + i] + W_b[i & 1023];
}

// sum 4 split-K partials + bias (predictions: 256x128)
__global__ void k_fcsum(const float* __restrict__ Fp, const float* __restrict__ fc_b,
                        float* __restrict__ outp) {
    int i = blockIdx.x * blockDim.x + threadIdx.x;   // 32768
    outp[i] = Fp[i] + Fp[32768 + i] + Fp[65536 + i] + Fp[98304 + i] + fc_b[i & 127];
}

// ---------------- launch ----------------

extern "C" void kernel_launch(void* const* d_in, const int* in_sizes, int n_in,
                              void* d_out, int out_size, void* d_ws, size_t ws_size,
                              hipStream_t stream) {
    const int*   x      = (const int*)  d_in[0];
    const float* es     = (const float*)d_in[1];
    const float* hidden = (const float*)d_in[2];
    const float* emb    = (const float*)d_in[4];
    const float* U_w    = (const float*)d_in[5];
    const float* U_b    = (const float*)d_in[6];
    const float* W_w    = (const float*)d_in[7];
    const float* W_b    = (const float*)d_in[8];
    const float* attn_w = (const float*)d_in[9];
    const float* W_ih0  = (const float*)d_in[11];
    const float* W_hh0  = (const float*)d_in[12];
    const float* b_ih0  = (const float*)d_in[13];
    const float* b_hh0  = (const float*)d_in[14];
    const float* W_ih1  = (const float*)d_in[15];
    const float* W_hh1  = (const float*)d_in[16];
    const float* b_ih1  = (const float*)d_in[17];
    const float* b_hh1  = (const float*)d_in[18];
    const float* fc_w   = (const float*)d_in[19];
    const float* fc_b   = (const float*)d_in[20];

    float* out        = (float*)d_out;
    float* out_pred   = out;
    float* out_hidden = out + 32768;
    float* out_attn   = out + 32768 + 524288;

    char* ws = (char*)d_ws;
    size_t off = 0;
    auto alloc = [&](size_t bytes) { char* p = ws + off; off += (bytes + 255) & ~(size_t)255; return p; };
    unsigned short* ES_BF  = (unsigned short*)alloc((size_t)16384 * 2048 * 2);
    unsigned short* UW_BF  = (unsigned short*)alloc((size_t)1024 * 2048 * 2);
    unsigned short* WW_BF  = (unsigned short*)alloc((size_t)1024 * 1024 * 2);
    unsigned short* FCW_BF = (unsigned short*)alloc((size_t)128 * 1024 * 2);
    unsigned short* H1_BF  = (unsigned short*)alloc((size_t)256 * 1024 * 2);
    unsigned short* B0     = (unsigned short*)alloc((size_t)4096 * 3328 * 2);
    unsigned short* B1     = (unsigned short*)alloc((size_t)4096 * 2048 * 2);
    unsigned short* A0     = (unsigned short*)alloc((size_t)256 * 3328 * 2);
    unsigned short* A1     = (unsigned short*)alloc((size_t)256 * 2048 * 2);
    unsigned short* FCA    = (unsigned short*)alloc((size_t)256 * 1024 * 2);
    float* WBUF  = (float*)alloc((size_t)256 * 1024 * 4);
    float* EPART = (float*)alloc((size_t)16384 * 16 * 4);
    float* WP    = (float*)alloc((size_t)4 * 256 * 1024 * 4);   // w partials; reused for fc partials
    float* G0P   = (float*)alloc((size_t)4 * 256 * 4096 * 4);   // GRU0 partials; reused for GRU1
    float* FCP   = WP;
    float* G1P   = G0P;

    // fused prep
    k_prep<<<28864, 256, 0, stream>>>(es, U_w, W_w, fc_w, hidden, W_ih0, W_hh0, W_ih1, W_hh1,
                                      ES_BF, UW_BF, WW_BF, FCW_BF, A0, A1, H1_BF, B0, B1);
    // w = hidden[1] @ W_w^T + W_b  (split-K 4)
    gemm_bt_sk<<<dim3(8, 2, 4), 256, 0, stream>>>(H1_BF, WW_BF, WP, 1024, 1024, 256);
    k_wsum<<<1024, 256, 0, stream>>>(WP, W_b, WBUF);
    // u-GEMM + fused energy epilogue (m201 8-phase structure)
    gemm_energy256<<<dim3(4, 64), 512, 0, stream>>>(ES_BF, UW_BF, attn_w, U_b, WBUF, EPART);
    // softmax + context + embedding -> out_attn, A0
    k_softctx<<<256, 256, 0, stream>>>(ES_BF, EPART, emb, x, out_attn, A0);
    // GRU layer 0 (split-K 4: 3328 = 4*832)
    gemm_bt_sk<<<dim3(32, 2, 4), 256, 0, stream>>>(A0, B0, G0P, 4096, 3328, 832);
    k_gru<<<1024, 256, 0, stream>>>(G0P, b_ih0, b_hh0, hidden, out_hidden, A1, 2048);
    // GRU layer 1 (split-K 4: 2048 = 4*512)
    gemm_bt_sk<<<dim3(32, 2, 4), 256, 0, stream>>>(A1, B1, G1P, 4096, 2048, 512);
    k_gru<<<1024, 256, 0, stream>>>(G1P, b_ih1, b_hh1, hidden + 262144, out_hidden + 262144, FCA, 1024);
    // predictions = h1 @ fc_w^T + fc_b (split-K 4)
    gemm_bt_sk<<<dim3(1, 2, 4), 256, 0, stream>>>(FCA, FCW_BF, FCP, 128, 1024, 256);
    k_fcsum<<<128, 256, 0, stream>>>(FCP, fc_b, out_pred);
}